// Round 11
// baseline (1098.428 us; speedup 1.0000x reference)
//
#include <hip/hip_runtime.h>

#define B_ 8
#define N_ 384
#define K_ 383
#define NT_ 4
#define SROW 456   // Sw row stride (floats): 300 tanh-part + 3*52 residual-part
#define SRES 300
#define NROW 24    // 6 waves * 4 groups of 16 lanes
#define HSTR 388   // h staging row stride (floats); lane-consecutive -> conflict-free

__device__ __forceinline__ float fast_tanh(float x) {
    float e = __expf(2.0f * x);
    return 1.0f - 2.0f / (e + 1.0f);
}

__global__ __launch_bounds__(384, 2)
void feat_kernel(const float* __restrict__ coords,
                 const int*   __restrict__ types,
                 const float* __restrict__ W0, const float* __restrict__ b0,
                 const float* __restrict__ W1, const float* __restrict__ b1,
                 const float* __restrict__ W2, const float* __restrict__ b2,
                 float* __restrict__ out)
{
    // Hl: per-THREAD h staging (column t). Written and read only by thread t ->
    // no barriers needed; exists solely so runtime loops can index h (rule #20).
    __shared__ float Hl[50 * HSTR];          // 77,600 B
    __shared__ float Sw[NROW * SROW];        // 43,776 B
    __shared__ float Sl[304];                //  1,216 B
    __shared__ unsigned short ksort[384];    //    768 B
    __shared__ int cnt[4], woff[4];          //     32 B  -> 123,392 B total

    const int t  = threadIdx.x;
    const int bn = blockIdx.x;
    const int b  = bn / N_;
    const int n  = bn % N_;
    const int tn = types[n];

    // ---- bucket-sort neighbors by type (wave-uniform weight reads) ----------
    if (t < 4) cnt[t] = 0;
    __syncthreads();
    int myty = 0;
    if (t < K_) {
        int jj = t + (t >= n);
        myty = types[jj];
        atomicAdd(&cnt[myty], 1);
    }
    __syncthreads();
    if (t == 0) {
        int r = 0;
        for (int q = 0; q < 4; ++q) { woff[q] = r; r += cnt[q]; }
    }
    __syncthreads();
    if (t < K_) {
        int slot = atomicAdd(&woff[myty], 1);
        ksort[slot] = (unsigned short)t;
    }
    __syncthreads();

    // ---- per-thread neighbor setup ------------------------------------------
    const bool active = (t < K_);
    int k = active ? (int)ksort[t] : 0;
    int j = k + (k >= n);
    if (!active) j = (n == 0) ? 1 : 0;
    const int ty  = types[j];
    const int idx = tn * NT_ + ty;

    const float* cb = coords + (size_t)b * N_ * 3;
    const float rx = cb[n*3+0] - cb[j*3+0];
    const float ry = cb[n*3+1] - cb[j*3+1];
    const float rz = cb[n*3+2] - cb[j*3+2];
    const float d2 = rx*rx + ry*ry + rz*rz;
    const float inv_d  = rsqrtf(d2);
    const float s      = inv_d;
    const float inv_d2 = inv_d * inv_d;
    const float a0 = active ? rx * inv_d2 : 0.0f;
    const float a1 = active ? ry * inv_d2 : 0.0f;
    const float a2 = active ? rz * inv_d2 : 0.0f;

    // ---- layer 0: 1 -> 25 (static, h0 in regs) ------------------------------
    float h0[25];
    {
        const float* w0p = W0 + idx * 25;
        const float* b0p = b0 + idx * 25;
        #pragma unroll
        for (int o = 0; o < 25; ++o)
            h0[o] = fast_tanh(s * w0p[o] + b0p[o]);
    }
    // stage h0 columns for the runtime layer-1 loop
    #pragma unroll
    for (int i = 0; i < 25; ++i) Hl[i * HSTR + t] = h0[i];

    // ---- layer 1: 25 -> 50, RUNTIME i-loop (h0 via LDS, h1 accums static) ---
    float h1[50];
    {
        const float* b1p = b1 + idx * 50;
        #pragma unroll
        for (int o2 = 0; o2 < 25; ++o2) {
            float2 bv = ((const float2*)b1p)[o2];
            h1[o2*2+0] = bv.x;
            h1[o2*2+1] = bv.y;
        }
        const float* w1p = W1 + idx * 1250;
        #pragma unroll 2
        for (int i = 0; i < 25; ++i) {
            const float hi = Hl[i * HSTR + t];
            const float2* wr = (const float2*)(w1p + i * 50);   // 8B aligned
            #pragma unroll
            for (int o2 = 0; o2 < 25; ++o2) {
                float2 w = wr[o2];
                h1[o2*2+0] += hi * w.x;
                h1[o2*2+1] += hi * w.y;
            }
        }
        #pragma unroll
        for (int o = 0; o < 50; ++o)
            h1[o] = fast_tanh(h1[o]) + h0[o % 25];   // h0 still in regs, static
    }

    const int  row    = t >> 4;             // 16-lane group id, 0..23
    const bool leader = ((t & 15) == 0);

    // ---- residual part of S: Sres[c][j] = sum_k a[k,c]*h1[k,j] --------------
    #pragma unroll
    for (int c = 0; c < 3; ++c) {
        const float ac = (c == 0) ? a0 : (c == 1) ? a1 : a2;
        float p[50];
        #pragma unroll
        for (int o = 0; o < 50; ++o) p[o] = ac * h1[o];
        #pragma unroll
        for (int st = 1; st <= 8; st <<= 1) {
            #pragma unroll
            for (int o = 0; o < 50; ++o)
                p[o] += __shfl_xor(p[o], st, 64);
        }
        if (leader) {
            float* dst = &Sw[row * SROW + SRES + c * 52];
            #pragma unroll
            for (int o4 = 0; o4 < 12; ++o4)
                ((float4*)dst)[o4] = make_float4(p[o4*4+0], p[o4*4+1],
                                                 p[o4*4+2], p[o4*4+3]);
            dst[48] = p[48];
            dst[49] = p[49];
        }
    }

    // stage h1 columns (overwrites h0 rows -- layer1 is done with them)
    #pragma unroll
    for (int o = 0; o < 50; ++o) Hl[o * HSTR + t] = h1[o];

    // ---- layer 2: 50 -> 100, RUNTIME c5 & i loops (h1 via LDS) --------------
    const float* w2base = W2 + idx * 5000;
    const float* b2p    = b2 + idx * 100;
    #pragma unroll 1
    for (int c5 = 0; c5 < 5; ++c5) {
        float g[20];
        const float4* b4 = (const float4*)(b2p + c5 * 20);      // 16B aligned
        #pragma unroll
        for (int o4 = 0; o4 < 5; ++o4) {
            float4 bv = b4[o4];
            g[o4*4+0] = bv.x; g[o4*4+1] = bv.y;
            g[o4*4+2] = bv.z; g[o4*4+3] = bv.w;
        }
        const float* w2p = w2base + c5 * 20;
        #pragma unroll 2
        for (int i = 0; i < 50; ++i) {
            const float hi = Hl[i * HSTR + t];
            const float4* wr = (const float4*)(w2p + i * 100);  // 16B aligned
            #pragma unroll
            for (int o4 = 0; o4 < 5; ++o4) {
                float4 w = wr[o4];
                g[o4*4+0] += hi * w.x;
                g[o4*4+1] += hi * w.y;
                g[o4*4+2] += hi * w.z;
                g[o4*4+3] += hi * w.w;
            }
        }
        #pragma unroll
        for (int o = 0; o < 20; ++o) g[o] = fast_tanh(g[o]);    // residual via Sres

        #pragma unroll
        for (int c = 0; c < 3; ++c) {
            const float ac = (c == 0) ? a0 : (c == 1) ? a1 : a2;
            float p[20];
            #pragma unroll
            for (int o = 0; o < 20; ++o) p[o] = ac * g[o];
            #pragma unroll
            for (int st = 1; st <= 8; st <<= 1) {
                #pragma unroll
                for (int o = 0; o < 20; ++o)
                    p[o] += __shfl_xor(p[o], st, 64);
            }
            if (leader) {
                float* dst = &Sw[row * SROW + c * 100 + c5 * 20];
                #pragma unroll
                for (int o4 = 0; o4 < 5; ++o4)
                    ((float4*)dst)[o4] = make_float4(p[o4*4+0], p[o4*4+1],
                                                     p[o4*4+2], p[o4*4+3]);
            }
        }
    }
    __syncthreads();

    // ---- final S reduction over 24 group rows -------------------------------
    if (t < 300) {
        const int c = t / 100;
        const int m = t - c * 100;
        const int jr = (m >= 50) ? m - 50 : m;
        float acc = 0.f;
        #pragma unroll 8
        for (int r = 0; r < NROW; ++r)
            acc += Sw[r * SROW + t] + Sw[r * SROW + SRES + c * 52 + jr];
        Sl[t] = acc;
    }
    __syncthreads();

    // ---- D[m][a] = sum_c S[c][m]*S[c][a] ------------------------------------
    {
        const int m = t >> 2, a = t & 3;
        float v = Sl[0*100+m]*Sl[0*100+a]
                + Sl[1*100+m]*Sl[1*100+a]
                + Sl[2*100+m]*Sl[2*100+a];
        out[(size_t)bn * 400 + t] = v;
        if (t < 16) {
            const int m2 = 96 + (t >> 2);
            float v2 = Sl[0*100+m2]*Sl[0*100+a]
                     + Sl[1*100+m2]*Sl[1*100+a]
                     + Sl[2*100+m2]*Sl[2*100+a];
            out[(size_t)bn * 400 + 384 + t] = v2;
        }
    }
}

extern "C" void kernel_launch(void* const* d_in, const int* in_sizes, int n_in,
                              void* d_out, int out_size, void* d_ws, size_t ws_size,
                              hipStream_t stream) {
    const float* coords = (const float*)d_in[0];
    const int*   types  = (const int*)  d_in[1];
    const float* W0 = (const float*)d_in[2];
    const float* b0 = (const float*)d_in[3];
    const float* W1 = (const float*)d_in[4];
    const float* b1 = (const float*)d_in[5];
    const float* W2 = (const float*)d_in[6];
    const float* b2 = (const float*)d_in[7];
    float* out = (float*)d_out;

    feat_kernel<<<dim3(B_ * N_), dim3(384), 0, stream>>>(
        coords, types, W0, b0, W1, b1, W2, b2, out);
}

// Round 14
// 928.673 us; speedup vs baseline: 1.1828x; 1.1828x over previous
//
#include <hip/hip_runtime.h>

#define B_ 8
#define N_ 384
#define K_ 383
#define NT_ 4
#define SROW 456   // Sw row stride (floats): 300 tanh-part + 3*52 residual-part
#define SRES 300
#define NROW 24    // 6 waves * 4 groups of 16 lanes

__device__ __forceinline__ float fast_tanh(float x) {
    float e = __expf(2.0f * x);
    return 1.0f - 2.0f / (e + 1.0f);
}

__global__ __launch_bounds__(384, 2)
void feat_kernel(const float* __restrict__ coords,
                 const int*   __restrict__ types,
                 const float* __restrict__ W0, const float* __restrict__ b0,
                 const float* __restrict__ W1, const float* __restrict__ b1,
                 const float* __restrict__ W2, const float* __restrict__ b2,
                 float* __restrict__ out)
{
    // Weights for the 4 type-pairs (tn,0..3) -- contiguous in the source
    // tensors since idx = tn*4 + ty. Read via broadcast ds_read in the MLP.
    __shared__ float Wl2[4 * 5000];          // 80,000 B
    __shared__ float Wl1[4 * 1250];          // 20,000 B
    __shared__ float Wl0[4 * 25];            //    400 B
    __shared__ float Bl0[4 * 25];            //    400 B
    __shared__ float Bl1[4 * 50];            //    800 B
    __shared__ float Bl2[4 * 100];           //  1,600 B
    __shared__ float Sw[NROW * SROW];        // 43,776 B
    __shared__ float Sl[304];                //  1,216 B
    __shared__ unsigned short ksort[384];    //    768 B
    __shared__ int cnt[4], woff[4];          //     32 B  -> 148,992 B total

    const int t  = threadIdx.x;
    const int bn = blockIdx.x;
    const int b  = bn / N_;
    const int n  = bn % N_;
    const int tn = types[n];

    // ---- stage weights global -> LDS (one-time, float4 throughout) ----------
    // All offsets are tn*4-based -> 16B-aligned for every tensor.
    {
        const float4* s2 = (const float4*)(W2 + tn * 4 * 5000);  // 5000 f4
        float4*       d2 = (float4*)Wl2;
        for (int i = t; i < 5000; i += 384) d2[i] = s2[i];
        const float4* s1 = (const float4*)(W1 + tn * 4 * 1250);  // 1250 f4
        float4*       d1 = (float4*)Wl1;
        for (int i = t; i < 1250; i += 384) d1[i] = s1[i];
        if (t < 25) {
            ((float4*)Wl0)[t]  = ((const float4*)(W0 + tn * 4 * 25))[t];
            ((float4*)Bl0)[t]  = ((const float4*)(b0 + tn * 4 * 25))[t];
        } else if (t < 75) {
            ((float4*)Bl1)[t - 25] = ((const float4*)(b1 + tn * 4 * 50))[t - 25];
        } else if (t < 175) {
            ((float4*)Bl2)[t - 75] = ((const float4*)(b2 + tn * 4 * 100))[t - 75];
        }
    }

    // ---- bucket-sort neighbors by type (wave-uniform weight reads) ----------
    if (t < 4) cnt[t] = 0;
    __syncthreads();
    int myty = 0;
    if (t < K_) {
        int jj = t + (t >= n);
        myty = types[jj];
        atomicAdd(&cnt[myty], 1);
    }
    __syncthreads();
    if (t == 0) {
        int r = 0;
        for (int q2 = 0; q2 < 4; ++q2) { woff[q2] = r; r += cnt[q2]; }
    }
    __syncthreads();
    if (t < K_) {
        int slot = atomicAdd(&woff[myty], 1);
        ksort[slot] = (unsigned short)t;
    }
    __syncthreads();   // also covers the weight staging above

    // ---- per-thread neighbor setup ------------------------------------------
    const bool active = (t < K_);
    int k = active ? (int)ksort[t] : 0;
    int j = k + (k >= n);
    if (!active) j = (n == 0) ? 1 : 0;
    const int q   = types[j];               // bucket id 0..3 (wave-uniform mostly)

    const float* cb = coords + (size_t)b * N_ * 3;
    const float rx = cb[n*3+0] - cb[j*3+0];
    const float ry = cb[n*3+1] - cb[j*3+1];
    const float rz = cb[n*3+2] - cb[j*3+2];
    const float d2v = rx*rx + ry*ry + rz*rz;
    const float inv_d  = rsqrtf(d2v);
    const float s      = inv_d;
    const float inv_d2 = inv_d * inv_d;
    const float a0 = active ? rx * inv_d2 : 0.0f;
    const float a1 = active ? ry * inv_d2 : 0.0f;
    const float a2 = active ? rz * inv_d2 : 0.0f;

    // ---- layer 0: 1 -> 25 (weights via LDS broadcast) -----------------------
    float h0[25];
    {
        const float* w0p = &Wl0[q * 25];
        const float* b0p = &Bl0[q * 25];
        #pragma unroll
        for (int o = 0; o < 25; ++o)
            h0[o] = fast_tanh(s * w0p[o] + b0p[o]);
    }

    // ---- layer 1: 25 -> 50, full unroll, weights via LDS --------------------
    float h1[50];
    {
        const float* b1p = &Bl1[q * 50];
        #pragma unroll
        for (int o2 = 0; o2 < 25; ++o2) {
            float2 bv = ((const float2*)b1p)[o2];
            h1[o2*2+0] = bv.x;
            h1[o2*2+1] = bv.y;
        }
        const float* w1p = &Wl1[q * 1250];
        #pragma unroll
        for (int i = 0; i < 25; ++i) {
            const float hi = h0[i];
            const float2* wr = (const float2*)(w1p + i * 50);   // 8B aligned
            #pragma unroll
            for (int o2 = 0; o2 < 25; ++o2) {
                float2 w = wr[o2];
                h1[o2*2+0] += hi * w.x;
                h1[o2*2+1] += hi * w.y;
            }
        }
        #pragma unroll
        for (int o = 0; o < 50; ++o)
            h1[o] = fast_tanh(h1[o]) + h0[o % 25];
    }

    const int  row    = t >> 4;             // 16-lane group id, 0..23
    const bool leader = ((t & 15) == 0);

    // ---- residual part of S: Sres[c][j] = sum_k a[k,c]*h1[k,j] --------------
    #pragma unroll
    for (int c = 0; c < 3; ++c) {
        const float ac = (c == 0) ? a0 : (c == 1) ? a1 : a2;
        float p[50];
        #pragma unroll
        for (int o = 0; o < 50; ++o) p[o] = ac * h1[o];
        #pragma unroll
        for (int st = 1; st <= 8; st <<= 1) {
            #pragma unroll
            for (int o = 0; o < 50; ++o)
                p[o] += __shfl_xor(p[o], st, 64);
        }
        if (leader) {
            float* dst = &Sw[row * SROW + SRES + c * 52];
            #pragma unroll
            for (int o4 = 0; o4 < 12; ++o4)
                ((float4*)dst)[o4] = make_float4(p[o4*4+0], p[o4*4+1],
                                                 p[o4*4+2], p[o4*4+3]);
            dst[48] = p[48];
            dst[49] = p[49];
        }
    }

    // ---- layer 2 (5 chunks of 20) fused with tanh-part S-accumulation -------
    const float* w2base = &Wl2[q * 5000];
    const float* b2p    = &Bl2[q * 100];
    #pragma unroll 1
    for (int c5 = 0; c5 < 5; ++c5) {
        float g[20];
        const float4* b4 = (const float4*)(b2p + c5 * 20);      // 16B aligned
        #pragma unroll
        for (int o4 = 0; o4 < 5; ++o4) {
            float4 bv = b4[o4];
            g[o4*4+0] = bv.x; g[o4*4+1] = bv.y;
            g[o4*4+2] = bv.z; g[o4*4+3] = bv.w;
        }
        const float* w2p = w2base + c5 * 20;
        #pragma unroll
        for (int i = 0; i < 50; ++i) {                  // full unroll: h1 static
            const float hi = h1[i];
            const float4* wr = (const float4*)(w2p + i * 100);  // 16B aligned
            #pragma unroll
            for (int o4 = 0; o4 < 5; ++o4) {
                float4 w = wr[o4];
                g[o4*4+0] += hi * w.x;
                g[o4*4+1] += hi * w.y;
                g[o4*4+2] += hi * w.z;
                g[o4*4+3] += hi * w.w;
            }
        }
        #pragma unroll
        for (int o = 0; o < 20; ++o) g[o] = fast_tanh(g[o]);    // residual via Sres

        #pragma unroll
        for (int c = 0; c < 3; ++c) {
            const float ac = (c == 0) ? a0 : (c == 1) ? a1 : a2;
            float p[20];
            #pragma unroll
            for (int o = 0; o < 20; ++o) p[o] = ac * g[o];
            #pragma unroll
            for (int st = 1; st <= 8; st <<= 1) {
                #pragma unroll
                for (int o = 0; o < 20; ++o)
                    p[o] += __shfl_xor(p[o], st, 64);
            }
            if (leader) {
                float* dst = &Sw[row * SROW + c * 100 + c5 * 20];
                #pragma unroll
                for (int o4 = 0; o4 < 5; ++o4)
                    ((float4*)dst)[o4] = make_float4(p[o4*4+0], p[o4*4+1],
                                                     p[o4*4+2], p[o4*4+3]);
            }
        }
    }
    __syncthreads();

    // ---- final S reduction over 24 group rows -------------------------------
    if (t < 300) {
        const int c = t / 100;
        const int m = t - c * 100;
        const int jr = (m >= 50) ? m - 50 : m;
        float acc = 0.f;
        #pragma unroll 8
        for (int r = 0; r < NROW; ++r)
            acc += Sw[r * SROW + t] + Sw[r * SROW + SRES + c * 52 + jr];
        Sl[t] = acc;
    }
    __syncthreads();

    // ---- D[m][a] = sum_c S[c][m]*S[c][a] ------------------------------------
    {
        const int m = t >> 2, a = t & 3;
        float v = Sl[0*100+m]*Sl[0*100+a]
                + Sl[1*100+m]*Sl[1*100+a]
                + Sl[2*100+m]*Sl[2*100+a];
        out[(size_t)bn * 400 + t] = v;
        if (t < 16) {
            const int m2 = 96 + (t >> 2);
            float v2 = Sl[0*100+m2]*Sl[0*100+a]
                     + Sl[1*100+m2]*Sl[1*100+a]
                     + Sl[2*100+m2]*Sl[2*100+a];
            out[(size_t)bn * 400 + 384 + t] = v2;
        }
    }
}

extern "C" void kernel_launch(void* const* d_in, const int* in_sizes, int n_in,
                              void* d_out, int out_size, void* d_ws, size_t ws_size,
                              hipStream_t stream) {
    const float* coords = (const float*)d_in[0];
    const int*   types  = (const int*)  d_in[1];
    const float* W0 = (const float*)d_in[2];
    const float* b0 = (const float*)d_in[3];
    const float* W1 = (const float*)d_in[4];
    const float* b1 = (const float*)d_in[5];
    const float* W2 = (const float*)d_in[6];
    const float* b2 = (const float*)d_in[7];
    float* out = (float*)d_out;

    feat_kernel<<<dim3(B_ * N_), dim3(384), 0, stream>>>(
        coords, types, W0, b0, W1, b1, W2, b2, out);
}

// Round 16
// 853.170 us; speedup vs baseline: 1.2875x; 1.0885x over previous
//
#include <hip/hip_runtime.h>

#define B_ 8
#define N_ 384
#define K_ 383
#define NT_ 4
#define TPB 576    // 9 waves: worst-case padded bucket total (383 + 3*63 -> 572)
#define SROW 456   // Sw row stride: 300 tanh-part + 3*52 residual-part
#define SRES 300
#define NROW 36    // TPB/16 groups of 16 lanes

__device__ __forceinline__ float fast_tanh(float x) {
    float e = __expf(2.0f * x);
    return 1.0f - 2.0f / (e + 1.0f);
}

// 16-lane sum on the VALU pipe via DPP row_shr (rocPRIM pattern); no DS traffic.
// After the chain, lane 15 of each 16-lane group holds the group sum.
template<int N>
__device__ __forceinline__ float row_shr_add(float x) {
    int y = __builtin_amdgcn_update_dpp(0, __float_as_int(x), 0x110 | N, 0xF, 0xF, true);
    return x + __int_as_float(y);
}
__device__ __forceinline__ float red16(float x) {
    x = row_shr_add<1>(x);
    x = row_shr_add<2>(x);
    x = row_shr_add<4>(x);
    x = row_shr_add<8>(x);
    return x;
}

__global__ __launch_bounds__(TPB, 2)
void feat_kernel(const float* __restrict__ coords,
                 const int*   __restrict__ types,
                 const float* __restrict__ W0, const float* __restrict__ b0,
                 const float* __restrict__ W1, const float* __restrict__ b1,
                 const float* __restrict__ W2, const float* __restrict__ b2,
                 float* __restrict__ out)
{
    __shared__ float Sw[NROW * SROW];        // 65,664 B partial S
    __shared__ float Sl[304];                //  1,216 B final S[3][100]
    __shared__ unsigned short ksort[384];    //    768 B
    __shared__ int cnt[4], woff[4], coff[4], poff[5];   // 68 B  -> ~67.7 KB

    const int t  = threadIdx.x;
    const int bn = blockIdx.x;
    const int b  = bn / N_;
    const int n  = bn % N_;
    const int tn = types[n];

    // ---- zero Sw (rows of inactive waves must read as 0) --------------------
    for (int i = t; i < NROW * SROW; i += TPB) Sw[i] = 0.0f;
    if (t < 4) cnt[t] = 0;
    __syncthreads();

    // ---- bucket-sort neighbors by type; pad buckets to wave multiples -------
    int myty = 0;
    if (t < K_) {
        int jj = t + (t >= n);
        myty = types[jj];
        atomicAdd(&cnt[myty], 1);
    }
    __syncthreads();
    if (t == 0) {
        int rc = 0, rp = 0;
        poff[0] = 0;
        for (int q2 = 0; q2 < 4; ++q2) {
            coff[q2] = rc; woff[q2] = rc; rc += cnt[q2];
            rp += (cnt[q2] + 63) & ~63;          // pad to multiple of 64
            poff[q2 + 1] = rp;
        }
    }
    __syncthreads();
    if (t < K_) {
        int slot = atomicAdd(&woff[myty], 1);
        ksort[slot] = (unsigned short)t;
    }
    __syncthreads();

    // ---- padded slot -> bucket (wave-uniform: poff are 64-multiples) --------
    const int  pq          = (t >= poff[1]) + (t >= poff[2]) + (t >= poff[3]);
    const bool wave_active = (t < poff[4]);
    const int  rel         = t - poff[pq];
    const bool active      = wave_active && (rel < cnt[pq]);
    int k = active ? (int)ksort[coff[pq] + rel] : 0;
    int j = k + (k >= n);
    if (!active) j = (n == 0) ? 1 : 0;

    const float* cb = coords + (size_t)b * N_ * 3;
    const float rx = cb[n*3+0] - cb[j*3+0];
    const float ry = cb[n*3+1] - cb[j*3+1];
    const float rz = cb[n*3+2] - cb[j*3+2];
    const float d2v = rx*rx + ry*ry + rz*rz;
    const float inv_d  = rsqrtf(d2v);
    const float s      = inv_d;
    const float inv_d2 = inv_d * inv_d;
    const float a0 = active ? rx * inv_d2 : 0.0f;   // pad lanes contribute 0
    const float a1 = active ? ry * inv_d2 : 0.0f;
    const float a2 = active ? rz * inv_d2 : 0.0f;

    if (wave_active) {   // wave-uniform branch; fully-pad waves skip the MLP
        // Wave-uniform weight index -> SGPR; weight loads become scalar (SMEM).
        const int idx_s = __builtin_amdgcn_readfirstlane(tn * NT_ + pq);

        // ---- layer 0: 1 -> 25 ----------------------------------------------
        float h0[25];
        {
            const float* __restrict__ w0p = W0 + idx_s * 25;
            const float* __restrict__ b0p = b0 + idx_s * 25;
            #pragma unroll
            for (int o = 0; o < 25; ++o)
                h0[o] = fast_tanh(s * w0p[o] + b0p[o]);
        }

        // ---- layer 1: 25 -> 50 (full unroll, scalar weight stream) ----------
        float h1[50];
        {
            const float* __restrict__ b1p = b1 + idx_s * 50;
            #pragma unroll
            for (int o2 = 0; o2 < 25; ++o2) {
                float2 bv = ((const float2*)b1p)[o2];
                h1[o2*2+0] = bv.x;
                h1[o2*2+1] = bv.y;
            }
            const float* __restrict__ w1p = W1 + idx_s * 1250;
            #pragma unroll
            for (int i = 0; i < 25; ++i) {
                const float hi = h0[i];
                const float2* wr = (const float2*)(w1p + i * 50);
                #pragma unroll
                for (int o2 = 0; o2 < 25; ++o2) {
                    float2 w = wr[o2];
                    h1[o2*2+0] += hi * w.x;
                    h1[o2*2+1] += hi * w.y;
                }
            }
            #pragma unroll
            for (int o = 0; o < 50; ++o)
                h1[o] = fast_tanh(h1[o]) + h0[o % 25];
        }

        const int  row    = t >> 4;
        const bool leader = ((t & 15) == 15);   // DPP sum lands in lane 15

        // ---- residual S part: Sres[c][j] = sum_k a[k,c]*h1[k,j] -------------
        #pragma unroll
        for (int c = 0; c < 3; ++c) {
            const float ac = (c == 0) ? a0 : (c == 1) ? a1 : a2;
            float p[50];
            #pragma unroll
            for (int o = 0; o < 50; ++o) p[o] = red16(ac * h1[o]);
            if (leader) {
                float* dst = &Sw[row * SROW + SRES + c * 52];
                #pragma unroll
                for (int o4 = 0; o4 < 12; ++o4)
                    ((float4*)dst)[o4] = make_float4(p[o4*4+0], p[o4*4+1],
                                                     p[o4*4+2], p[o4*4+3]);
                dst[48] = p[48];
                dst[49] = p[49];
            }
        }

        // ---- layer 2 (5 chunks of 20) + tanh-part S accumulation ------------
        const float* __restrict__ w2base = W2 + idx_s * 5000;
        const float* __restrict__ b2p    = b2 + idx_s * 100;
        #pragma unroll 1
        for (int c5 = 0; c5 < 5; ++c5) {
            float g[20];
            const float4* b4 = (const float4*)(b2p + c5 * 20);
            #pragma unroll
            for (int o4 = 0; o4 < 5; ++o4) {
                float4 bv = b4[o4];
                g[o4*4+0] = bv.x; g[o4*4+1] = bv.y;
                g[o4*4+2] = bv.z; g[o4*4+3] = bv.w;
            }
            const float* w2p = w2base + c5 * 20;
            #pragma unroll
            for (int i = 0; i < 50; ++i) {
                const float hi = h1[i];
                const float4* wr = (const float4*)(w2p + i * 100);
                #pragma unroll
                for (int o4 = 0; o4 < 5; ++o4) {
                    float4 w = wr[o4];
                    g[o4*4+0] += hi * w.x;
                    g[o4*4+1] += hi * w.y;
                    g[o4*4+2] += hi * w.z;
                    g[o4*4+3] += hi * w.w;
                }
            }
            #pragma unroll
            for (int o = 0; o < 20; ++o) g[o] = fast_tanh(g[o]);

            #pragma unroll
            for (int c = 0; c < 3; ++c) {
                const float ac = (c == 0) ? a0 : (c == 1) ? a1 : a2;
                float p[20];
                #pragma unroll
                for (int o = 0; o < 20; ++o) p[o] = red16(ac * g[o]);
                if (leader) {
                    float* dst = &Sw[row * SROW + c * 100 + c5 * 20];
                    #pragma unroll
                    for (int o4 = 0; o4 < 5; ++o4)
                        ((float4*)dst)[o4] = make_float4(p[o4*4+0], p[o4*4+1],
                                                         p[o4*4+2], p[o4*4+3]);
                }
            }
        }
    }
    __syncthreads();

    // ---- final S reduction over 36 group rows (zeroed rows harmless) --------
    if (t < 300) {
        const int c = t / 100;
        const int m = t - c * 100;
        const int jr = (m >= 50) ? m - 50 : m;
        float acc = 0.f;
        #pragma unroll 6
        for (int r = 0; r < NROW; ++r)
            acc += Sw[r * SROW + t] + Sw[r * SROW + SRES + c * 52 + jr];
        Sl[t] = acc;
    }
    __syncthreads();

    // ---- D[m][a] = sum_c S[c][m]*S[c][a]; 400 outputs, 576 threads ----------
    if (t < 400) {
        const int m = t >> 2, a = t & 3;
        float v = Sl[0*100+m]*Sl[0*100+a]
                + Sl[1*100+m]*Sl[1*100+a]
                + Sl[2*100+m]*Sl[2*100+a];
        out[(size_t)bn * 400 + t] = v;
    }
}

extern "C" void kernel_launch(void* const* d_in, const int* in_sizes, int n_in,
                              void* d_out, int out_size, void* d_ws, size_t ws_size,
                              hipStream_t stream) {
    const float* coords = (const float*)d_in[0];
    const int*   types  = (const int*)  d_in[1];
    const float* W0 = (const float*)d_in[2];
    const float* b0 = (const float*)d_in[3];
    const float* W1 = (const float*)d_in[4];
    const float* b1 = (const float*)d_in[5];
    const float* W2 = (const float*)d_in[6];
    const float* b2 = (const float*)d_in[7];
    float* out = (float*)d_out;

    feat_kernel<<<dim3(B_ * N_), dim3(TPB), 0, stream>>>(
        coords, types, W0, b0, W1, b1, W2, b2, out);
}